// Round 1
// baseline (1443.854 us; speedup 1.0000x reference)
//
#include <hip/hip_runtime.h>
#include <math.h>

#define NN 32768      // nodes
#define EE 524288     // edges
#define CC 128        // in channels
#define CTWO 256      // 2C
#define ACTE 262143   // active edges: (i+1) < E*(1-0.5)
#define NBUK 262144   // sort buckets (2^18)

// output offsets (floats)
#define OFF_NEWX   0
#define OFF_SCORE  4194304
#define OFF_CSCORE 4718592
#define OFF_NEI    4751360
#define OFF_NBATCH 5799936
#define OFF_CLUST  5832704
#define OFF_NUMC   5865472

#define ALOADI(p)   __hip_atomic_load((p), __ATOMIC_RELAXED, __HIP_MEMORY_SCOPE_AGENT)
#define ASTOREI(p,v) __hip_atomic_store((p),(v), __ATOMIC_RELAXED, __HIP_MEMORY_SCOPE_AGENT)

// ---------------- GEMM1: A[u]=W2[:, :128]*x_u, B[u]=W2[:,128:]*x_u (fp64) ----------------
// block: 32 nodes x 256 outputs; gridDim.y: 0 -> A, 1 -> B
__global__ __launch_bounds__(256) void k_gemm1(const float* __restrict__ x,
                                               const float* __restrict__ W2,
                                               double* __restrict__ Abuf,
                                               double* __restrict__ Bbuf) {
    __shared__ float xs[32 * 33];
    __shared__ float wsh[256 * 33];
    const int t = threadIdx.x;
    const int tx = t & 31, ty = t >> 5;
    const int nBase = blockIdx.x * 32;
    const int half = blockIdx.y;
    const float* W2base = W2 + half * CC;   // W2[j*256 + half*128 + k]
    double acc[4][8];
#pragma unroll
    for (int i = 0; i < 4; i++)
#pragma unroll
        for (int j = 0; j < 8; j++) acc[i][j] = 0.0;

    for (int kc = 0; kc < 4; ++kc) {
        // x tile: 32 nodes x 32 k
        {
            int l = t * 4;
            int n = l >> 5, k0 = l & 31;
            const float* gp = &x[(nBase + n) * CC + kc * 32 + k0];
#pragma unroll
            for (int q = 0; q < 4; q++) xs[n * 33 + k0 + q] = gp[q];
        }
        // W tile: 256 j x 32 k  (thread t: k = t&31, rows j = (t>>5) + 8*i)
#pragma unroll
        for (int i = 0; i < 32; i++) {
            int l = t + 256 * i;
            int j = l >> 5, k = l & 31;
            wsh[j * 33 + k] = W2base[j * CTWO + kc * 32 + k];
        }
        __syncthreads();
        for (int k = 0; k < 32; k++) {
            double xv[4], wv[8];
#pragma unroll
            for (int ni = 0; ni < 4; ni++) xv[ni] = (double)xs[(ty * 4 + ni) * 33 + k];
#pragma unroll
            for (int m = 0; m < 8; m++) wv[m] = (double)wsh[(tx + 32 * m) * 33 + k];
#pragma unroll
            for (int ni = 0; ni < 4; ni++)
#pragma unroll
                for (int m = 0; m < 8; m++) acc[ni][m] = fma(xv[ni], wv[m], acc[ni][m]);
        }
        __syncthreads();
    }
    double* outb = (half == 0) ? Abuf : Bbuf;
#pragma unroll
    for (int ni = 0; ni < 4; ni++) {
        int u = nBase + ty * 4 + ni;
#pragma unroll
        for (int m = 0; m < 8; m++) outb[(size_t)u * CTWO + tx + 32 * m] = acc[ni][m];
    }
}

// ---------------- edge scoring: z = W1 . relu(A[s]+B[t]+b2) + b1; sigmoid (fp64) ----------------
__global__ __launch_bounds__(256) void k_edge_score(const double* __restrict__ Abuf,
                                                    const double* __restrict__ Bbuf,
                                                    const int* __restrict__ src,
                                                    const int* __restrict__ dst,
                                                    const float* __restrict__ b2,
                                                    const float* __restrict__ W1,
                                                    const float* __restrict__ b1,
                                                    double* __restrict__ score64,
                                                    float* __restrict__ scoreOut) {
    const int wave = threadIdx.x >> 6, lane = threadIdx.x & 63;
    const int e = blockIdx.x * 4 + wave;
    const int s = src[e], t = dst[e];
    const double* Ap = Abuf + (size_t)s * CTWO;
    const double* Bp = Bbuf + (size_t)t * CTWO;
    double z = 0.0;
#pragma unroll
    for (int m = 0; m < 4; m++) {
        int j = lane + 64 * m;
        double pre = Ap[j] + Bp[j] + (double)b2[j];
        double h = pre > 0.0 ? pre : 0.0;
        z = fma((double)W1[j], h, z);
    }
    for (int off = 32; off > 0; off >>= 1) z += __shfl_down(z, off);
    if (lane == 0) {
        z += (double)b1[0];
        double sg = 1.0 / (1.0 + exp(-z));
        score64[e] = sg;
        scoreOut[e] = (float)sg;
    }
}

// ---------------- bucket sort by (score desc, idx asc) ----------------
__device__ __forceinline__ int bucket_of(double s) {
    int b = (NBUK - 1) - (int)(s * (double)NBUK);   // truncation = floor (s >= 0)
    if (b < 0) b = 0;
    if (b > NBUK - 1) b = NBUK - 1;
    return b;
}

__global__ void k_bucket_count(const double* __restrict__ score64, unsigned* __restrict__ cnt) {
    int e = blockIdx.x * blockDim.x + threadIdx.x;
    if (e < EE) atomicAdd(&cnt[bucket_of(score64[e])], 1u);
}

__global__ __launch_bounds__(1024) void k_scan_offs(const unsigned* __restrict__ cnt,
                                                    unsigned* __restrict__ offs) {
    __shared__ unsigned sums[1024];
    const int t = threadIdx.x;
    const int CH = NBUK / 1024;   // 256
    const int base = t * CH;
    unsigned s = 0;
    const uint4* c4 = reinterpret_cast<const uint4*>(cnt + base);
    for (int i = 0; i < CH / 4; i++) { uint4 v = c4[i]; s += v.x + v.y + v.z + v.w; }
    sums[t] = s;
    __syncthreads();
    for (int off = 1; off < 1024; off <<= 1) {
        unsigned v = (t >= off) ? sums[t - off] : 0u;
        __syncthreads();
        sums[t] += v;
        __syncthreads();
    }
    unsigned run = (t == 0) ? 0u : sums[t - 1];
    for (int i = 0; i < CH; i++) { unsigned c = cnt[base + i]; offs[base + i] = run; run += c; }
}

__global__ void k_scatter(const double* __restrict__ score64, const unsigned* __restrict__ offs,
                          unsigned* __restrict__ curb, unsigned* __restrict__ slot) {
    int e = blockIdx.x * blockDim.x + threadIdx.x;
    if (e >= EE) return;
    int b = bucket_of(score64[e]);
    unsigned p = offs[b] + atomicAdd(&curb[b], 1u);
    slot[p] = (unsigned)e;
}

// one thread per bucket: selection sort (score desc, idx asc); emit rank-ordered endpoints/scores
__global__ void k_bucket_sort(const unsigned* __restrict__ cnt, const unsigned* __restrict__ offs,
                              unsigned* __restrict__ slot, const double* __restrict__ score64,
                              const int* __restrict__ src, const int* __restrict__ dst,
                              int* __restrict__ spArr, int* __restrict__ tpArr,
                              float* __restrict__ sc32) {
    int b = blockIdx.x * blockDim.x + threadIdx.x;
    if (b >= NBUK) return;
    int n = (int)cnt[b];
    if (n == 0) return;
    unsigned o = offs[b];
    for (int i = 0; i < n; i++) {
        int bi = i;
        unsigned be = slot[o + i];
        double bs = score64[be];
        for (int j = i + 1; j < n; j++) {
            unsigned e2 = slot[o + j];
            double s2 = score64[e2];
            if (s2 > bs || (s2 == bs && e2 < be)) { bi = j; be = e2; bs = s2; }
        }
        if (bi != i) { slot[o + bi] = slot[o + i]; slot[o + i] = be; }
        spArr[o + i] = src[be];
        tpArr[o + i] = dst[be];
        sc32[o + i] = (float)bs;
    }
}

__global__ void k_init_list(unsigned* __restrict__ list0, int* __restrict__ counts) {
    int r = blockIdx.x * blockDim.x + threadIdx.x;
    if (r < ACTE) list0[r] = (unsigned)r;
    if (r == 0) { counts[0] = ACTE; counts[1] = 0; }
}

// ---------------- handshake matching (== sequential greedy by rank) ----------------
// P1: alive edges atomicMin rank into bc at both endpoints; reset bo for next round; reset other count
__global__ void k_mp1(const int* __restrict__ sp, const int* __restrict__ tp,
                      const unsigned* __restrict__ Lc, int* __restrict__ counts, int cur,
                      unsigned* __restrict__ bc, unsigned* __restrict__ bo,
                      const unsigned* __restrict__ dead) {
    const unsigned gid = blockIdx.x * blockDim.x + threadIdx.x;
    const unsigned gsz = gridDim.x * blockDim.x;
    const int n = counts[cur];
    if (gid == 0) counts[1 - cur] = 0;
    for (unsigned i = gid; i < (unsigned)n; i += gsz) {
        unsigned r = Lc[i];
        int s = sp[r], t = tp[r];
        if (!dead[s] && !dead[t]) { atomicMin(&bc[s], r); atomicMin(&bc[t], r); }
    }
    for (unsigned u = gid; u < NN; u += gsz) bo[u] = 0xFFFFFFFFu;
}

// P2: select locally-dominant edges, kill endpoints, compact survivors
__global__ void k_mp2(const int* __restrict__ sp, const int* __restrict__ tp,
                      const unsigned* __restrict__ Lc, unsigned* __restrict__ Ln,
                      int* __restrict__ counts, int cur,
                      const unsigned* __restrict__ bc,
                      unsigned* __restrict__ dead, unsigned* __restrict__ sel) {
    const unsigned gid = blockIdx.x * blockDim.x + threadIdx.x;
    const unsigned gsz = gridDim.x * blockDim.x;
    const int n = counts[cur];
    for (unsigned i = gid; i < (unsigned)n; i += gsz) {
        unsigned r = Lc[i];
        int s = sp[r], t = tp[r];
        if (ALOADI(&dead[s]) || ALOADI(&dead[t])) continue;
        if (bc[s] == r && bc[t] == r) {
            sel[r] = 1u;
            ASTOREI(&dead[s], 1u);
            ASTOREI(&dead[t], 1u);
        } else {
            int p = atomicAdd(&counts[1 - cur], 1);
            Ln[p] = r;
        }
    }
}

// single-block tail: loop rounds until list empty (atomic loads for atomically-written data)
__global__ __launch_bounds__(1024) void k_mtail(const int* __restrict__ sp,
                                                const int* __restrict__ tp,
                                                unsigned* __restrict__ listA,
                                                unsigned* __restrict__ listB,
                                                int* __restrict__ counts, int cur0,
                                                unsigned* __restrict__ best0,
                                                unsigned* __restrict__ best1,
                                                unsigned* __restrict__ dead,
                                                unsigned* __restrict__ sel) {
    const int tid = threadIdx.x, tsz = blockDim.x;
    int cur = cur0;
    while (true) {
        int n = ALOADI(&counts[cur]);
        if (tid == 0) ASTOREI(&counts[1 - cur], 0);
        __syncthreads();
        if (n == 0) break;
        unsigned* Lc = cur ? listB : listA;
        unsigned* Ln = cur ? listA : listB;
        unsigned* bc = cur ? best1 : best0;
        unsigned* bo = cur ? best0 : best1;
        for (int i = tid; i < n; i += tsz) {
            unsigned r = Lc[i];
            int s = sp[r], t = tp[r];
            if (!dead[s] && !dead[t]) { atomicMin(&bc[s], r); atomicMin(&bc[t], r); }
        }
        for (int u = tid; u < NN; u += tsz) bo[u] = 0xFFFFFFFFu;
        __syncthreads();
        for (int i = tid; i < n; i += tsz) {
            unsigned r = Lc[i];
            int s = sp[r], t = tp[r];
            if (dead[s] || dead[t]) continue;
            unsigned bs_ = ALOADI(&bc[s]);
            unsigned bt_ = ALOADI(&bc[t]);
            if (bs_ == r && bt_ == r) {
                sel[r] = 1u;
                dead[s] = 1u;
                dead[t] = 1u;
            } else {
                int p = atomicAdd(&counts[1 - cur], 1);
                Ln[p] = r;
            }
        }
        __syncthreads();
        cur ^= 1;
    }
}

// ---------------- epilogue ----------------
__global__ void k_init_out(float* __restrict__ cscore, float* __restrict__ nbatch) {
    int i = blockIdx.x * blockDim.x + threadIdx.x;
    if (i < NN) { cscore[i] = 100.0f; nbatch[i] = 0.0f; }
}

// single block: exclusive scan of sel -> merge order; assign merged cluster ids
__global__ __launch_bounds__(1024) void k_sel_fill(const unsigned* __restrict__ sel,
                                                   const int* __restrict__ sp,
                                                   const int* __restrict__ tp,
                                                   const float* __restrict__ sc32,
                                                   int* __restrict__ cluster,
                                                   int* __restrict__ mergeS,
                                                   int* __restrict__ mergeT,
                                                   float* __restrict__ cscoreOut,
                                                   int* __restrict__ scalars) {
    __shared__ unsigned sums[1024];
    const int t = threadIdx.x;
    const int CH = (ACTE + 1023) / 1024;   // 256
    const int base = t * CH;
    unsigned s = 0;
    for (int i = 0; i < CH; i++) {
        int r = base + i;
        if (r < ACTE) s += sel[r];
    }
    sums[t] = s;
    __syncthreads();
    for (int off = 1; off < 1024; off <<= 1) {
        unsigned v = (t >= off) ? sums[t - off] : 0u;
        __syncthreads();
        sums[t] += v;
        __syncthreads();
    }
    unsigned run = (t == 0) ? 0u : sums[t - 1];
    for (int i = 0; i < CH; i++) {
        int r = base + i;
        if (r >= ACTE) break;
        if (sel[r]) {
            int i0 = (int)run;
            run++;
            int s_ = sp[r], t_ = tp[r];
            cluster[s_] = i0;
            cluster[t_] = i0;
            mergeS[i0] = s_;
            mergeT[i0] = t_;
            cscoreOut[i0] = sc32[r];
        }
    }
    if (t == 0) scalars[0] = (int)0;  // placeholder, overwritten below by t==1023? no: use sums
    __syncthreads();
    if (t == 0) scalars[0] = (int)sums[1023];   // M = total merges
}

// single block: survivors -> singleton clusters in node order
__global__ __launch_bounds__(1024) void k_surv_fill(const unsigned* __restrict__ dead,
                                                    int* __restrict__ cluster,
                                                    int* __restrict__ survN,
                                                    int* __restrict__ scalars,
                                                    float* __restrict__ numcOut) {
    __shared__ unsigned sums[1024];
    const int t = threadIdx.x;
    const int CH = NN / 1024;   // 32
    const int base = t * CH;
    unsigned s = 0;
    for (int i = 0; i < CH; i++) s += (dead[base + i] == 0u) ? 1u : 0u;
    sums[t] = s;
    __syncthreads();
    for (int off = 1; off < 1024; off <<= 1) {
        unsigned v = (t >= off) ? sums[t - off] : 0u;
        __syncthreads();
        sums[t] += v;
        __syncthreads();
    }
    const int M = scalars[0];
    unsigned run = (t == 0) ? 0u : sums[t - 1];
    for (int i = 0; i < CH; i++) {
        int u = base + i;
        if (dead[u] == 0u) {
            cluster[u] = M + (int)run;
            survN[run] = u;
            run++;
        }
    }
    __syncthreads();
    if (t == 0) {
        int numc = M + (int)sums[1023];
        scalars[1] = numc;
        numcOut[0] = (float)numc;
    }
}

__global__ void k_newx(const float* __restrict__ x, const int* __restrict__ mergeS,
                       const int* __restrict__ mergeT, const int* __restrict__ survN,
                       const int* __restrict__ scalars, float* __restrict__ outx) {
    int gidx = blockIdx.x * blockDim.x + threadIdx.x;
    int c = gidx >> 7;
    int j = gidx & 127;
    const int M = scalars[0], numc = scalars[1];
    float v = 0.0f;
    if (c < M) {
        int s = mergeS[c], t = mergeT[c];
        v = x[s * CC + j] + (s != t ? x[t * CC + j] : 0.0f);
    } else if (c < numc) {
        int u = survN[c - M];
        v = x[u * CC + j];
    }
    outx[gidx] = v;
}

__global__ void k_final(const int* __restrict__ ei, const int* __restrict__ batch,
                        const int* __restrict__ cluster, float* __restrict__ neiOut,
                        float* __restrict__ nbatch, float* __restrict__ clusterOut) {
    int i = blockIdx.x * blockDim.x + threadIdx.x;
    if (i < 2 * EE) neiOut[i] = (float)cluster[ei[i]];
    if (i < NN) {
        clusterOut[i] = (float)cluster[i];
        nbatch[cluster[i]] = (float)batch[i];
    }
}

// ---------------- host ----------------
extern "C" void kernel_launch(void* const* d_in, const int* in_sizes, int n_in,
                              void* d_out, int out_size, void* d_ws, size_t ws_size,
                              hipStream_t stream) {
    const float* x  = (const float*)d_in[0];
    const float* W2 = (const float*)d_in[2];
    const float* b2 = (const float*)d_in[3];
    const float* W1 = (const float*)d_in[4];
    const float* b1 = (const float*)d_in[5];
    const int* ei   = (const int*)d_in[6];
    const int* bat  = (const int*)d_in[7];
    const int* src = ei;
    const int* dst = ei + EE;
    float* out = (float*)d_out;

    char* p = (char*)d_ws;
    auto take = [&](size_t bytes) -> char* {
        char* r = p;
        p += (bytes + 255) & ~(size_t)255;
        return r;
    };
    double*   Abuf    = (double*)take((size_t)NN * CTWO * 8);
    double*   Bbuf    = (double*)take((size_t)NN * CTWO * 8);
    double*   score64 = (double*)take((size_t)EE * 8);
    unsigned* cnt     = (unsigned*)take((size_t)NBUK * 4);
    unsigned* offs    = (unsigned*)take((size_t)NBUK * 4);
    unsigned* curb    = (unsigned*)take((size_t)NBUK * 4);
    unsigned* slot    = (unsigned*)take((size_t)EE * 4);
    int*      spArr   = (int*)take((size_t)EE * 4);
    int*      tpArr   = (int*)take((size_t)EE * 4);
    float*    sc32    = (float*)take((size_t)EE * 4);
    unsigned* list0   = (unsigned*)take((size_t)NBUK * 4);
    unsigned* list1   = (unsigned*)take((size_t)NBUK * 4);
    unsigned* best0   = (unsigned*)take((size_t)NN * 4);
    unsigned* best1   = (unsigned*)take((size_t)NN * 4);
    unsigned* dead    = (unsigned*)take((size_t)NN * 4);
    unsigned* sel     = (unsigned*)take((size_t)NBUK * 4);
    int*      cluster = (int*)take((size_t)NN * 4);
    int*      mergeS  = (int*)take((size_t)NN * 4);
    int*      mergeT  = (int*)take((size_t)NN * 4);
    int*      survN   = (int*)take((size_t)NN * 4);
    int*      counts  = (int*)take(256);
    int*      scalars = (int*)take(256);

    hipMemsetAsync(cnt, 0, (size_t)NBUK * 4, stream);
    hipMemsetAsync(curb, 0, (size_t)NBUK * 4, stream);
    hipMemsetAsync(sel, 0, (size_t)NBUK * 4, stream);
    hipMemsetAsync(dead, 0, (size_t)NN * 4, stream);
    hipMemsetAsync(best0, 0xFF, (size_t)NN * 4, stream);
    hipMemsetAsync(best1, 0xFF, (size_t)NN * 4, stream);

    k_gemm1<<<dim3(NN / 32, 2), 256, 0, stream>>>(x, W2, Abuf, Bbuf);
    k_edge_score<<<EE / 4, 256, 0, stream>>>(Abuf, Bbuf, src, dst, b2, W1, b1, score64,
                                             out + OFF_SCORE);
    k_bucket_count<<<EE / 256, 256, 0, stream>>>(score64, cnt);
    k_scan_offs<<<1, 1024, 0, stream>>>(cnt, offs);
    k_scatter<<<EE / 256, 256, 0, stream>>>(score64, offs, curb, slot);
    k_bucket_sort<<<NBUK / 256, 256, 0, stream>>>(cnt, offs, slot, score64, src, dst, spArr,
                                                  tpArr, sc32);
    k_init_list<<<NBUK / 256, 256, 0, stream>>>(list0, counts);

    const int NBIG = 10;
    for (int r = 0; r < NBIG; ++r) {
        int cur = r & 1;
        unsigned* Lc = cur ? list1 : list0;
        unsigned* Ln = cur ? list0 : list1;
        unsigned* bc = cur ? best1 : best0;
        unsigned* bo = cur ? best0 : best1;
        k_mp1<<<1024, 256, 0, stream>>>(spArr, tpArr, Lc, counts, cur, bc, bo, dead);
        k_mp2<<<1024, 256, 0, stream>>>(spArr, tpArr, Lc, Ln, counts, cur, bc, dead, sel);
    }
    k_mtail<<<1, 1024, 0, stream>>>(spArr, tpArr, list0, list1, counts, NBIG & 1, best0, best1,
                                    dead, sel);

    k_init_out<<<NN / 256, 256, 0, stream>>>(out + OFF_CSCORE, out + OFF_NBATCH);
    k_sel_fill<<<1, 1024, 0, stream>>>(sel, spArr, tpArr, sc32, cluster, mergeS, mergeT,
                                       out + OFF_CSCORE, scalars);
    k_surv_fill<<<1, 1024, 0, stream>>>(dead, cluster, survN, scalars, out + OFF_NUMC);
    k_newx<<<(NN * CC) / 256, 256, 0, stream>>>(x, mergeS, mergeT, survN, scalars, out + OFF_NEWX);
    k_final<<<(2 * EE) / 256, 256, 0, stream>>>(ei, bat, cluster, out + OFF_NEI, out + OFF_NBATCH,
                                                out + OFF_CLUST);
}

// Round 2
// 1050.264 us; speedup vs baseline: 1.3748x; 1.3748x over previous
//
#include <hip/hip_runtime.h>
#include <math.h>

#define NN 32768      // nodes
#define EE 524288     // edges
#define CC 128        // in channels
#define CTWO 256      // 2C
#define ACTE 262143   // active edges: (i+1) < E*(1-0.5)
#define NBUK 262144   // sort buckets (2^18)

// output offsets (floats)
#define OFF_NEWX   0
#define OFF_SCORE  4194304
#define OFF_CSCORE 4718592
#define OFF_NEI    4751360
#define OFF_NBATCH 5799936
#define OFF_CLUST  5832704
#define OFF_NUMC   5865472

#define ALOADI(p)   __hip_atomic_load((p), __ATOMIC_RELAXED, __HIP_MEMORY_SCOPE_AGENT)
#define ASTOREI(p,v) __hip_atomic_store((p),(v), __ATOMIC_RELAXED, __HIP_MEMORY_SCOPE_AGENT)

// ---------------- GEMM1: A[u]=W2[:, :128]*x_u, B[u]=W2[:,128:]*x_u (fp64) ----------------
__global__ __launch_bounds__(256) void k_gemm1(const float* __restrict__ x,
                                               const float* __restrict__ W2,
                                               double* __restrict__ Abuf,
                                               double* __restrict__ Bbuf) {
    __shared__ float xs[32 * 33];
    __shared__ float wsh[256 * 33];
    const int t = threadIdx.x;
    const int tx = t & 31, ty = t >> 5;
    const int nBase = blockIdx.x * 32;
    const int half = blockIdx.y;
    const float* W2base = W2 + half * CC;
    double acc[4][8];
#pragma unroll
    for (int i = 0; i < 4; i++)
#pragma unroll
        for (int j = 0; j < 8; j++) acc[i][j] = 0.0;

    for (int kc = 0; kc < 4; ++kc) {
        {
            int l = t * 4;
            int n = l >> 5, k0 = l & 31;
            const float* gp = &x[(nBase + n) * CC + kc * 32 + k0];
#pragma unroll
            for (int q = 0; q < 4; q++) xs[n * 33 + k0 + q] = gp[q];
        }
#pragma unroll
        for (int i = 0; i < 32; i++) {
            int l = t + 256 * i;
            int j = l >> 5, k = l & 31;
            wsh[j * 33 + k] = W2base[j * CTWO + kc * 32 + k];
        }
        __syncthreads();
        for (int k = 0; k < 32; k++) {
            double xv[4], wv[8];
#pragma unroll
            for (int ni = 0; ni < 4; ni++) xv[ni] = (double)xs[(ty * 4 + ni) * 33 + k];
#pragma unroll
            for (int m = 0; m < 8; m++) wv[m] = (double)wsh[(tx + 32 * m) * 33 + k];
#pragma unroll
            for (int ni = 0; ni < 4; ni++)
#pragma unroll
                for (int m = 0; m < 8; m++) acc[ni][m] = fma(xv[ni], wv[m], acc[ni][m]);
        }
        __syncthreads();
    }
    double* outb = (half == 0) ? Abuf : Bbuf;
#pragma unroll
    for (int ni = 0; ni < 4; ni++) {
        int u = nBase + ty * 4 + ni;
#pragma unroll
        for (int m = 0; m < 8; m++) outb[(size_t)u * CTWO + tx + 32 * m] = acc[ni][m];
    }
}

// ---------------- edge scoring (fp64) ----------------
__global__ __launch_bounds__(256) void k_edge_score(const double* __restrict__ Abuf,
                                                    const double* __restrict__ Bbuf,
                                                    const int* __restrict__ src,
                                                    const int* __restrict__ dst,
                                                    const float* __restrict__ b2,
                                                    const float* __restrict__ W1,
                                                    const float* __restrict__ b1,
                                                    double* __restrict__ score64,
                                                    float* __restrict__ scoreOut) {
    const int wave = threadIdx.x >> 6, lane = threadIdx.x & 63;
    const int e = blockIdx.x * 4 + wave;
    const int s = src[e], t = dst[e];
    const double* Ap = Abuf + (size_t)s * CTWO;
    const double* Bp = Bbuf + (size_t)t * CTWO;
    double z = 0.0;
#pragma unroll
    for (int m = 0; m < 4; m++) {
        int j = lane + 64 * m;
        double pre = Ap[j] + Bp[j] + (double)b2[j];
        double h = pre > 0.0 ? pre : 0.0;
        z = fma((double)W1[j], h, z);
    }
    for (int off = 32; off > 0; off >>= 1) z += __shfl_down(z, off);
    if (lane == 0) {
        z += (double)b1[0];
        double sg = 1.0 / (1.0 + exp(-z));
        score64[e] = sg;
        scoreOut[e] = (float)sg;
    }
}

// ---------------- bucket sort by (score desc, idx asc) ----------------
__device__ __forceinline__ int bucket_of(double s) {
    int b = (NBUK - 1) - (int)(s * (double)NBUK);
    if (b < 0) b = 0;
    if (b > NBUK - 1) b = NBUK - 1;
    return b;
}

__global__ void k_bucket_count(const double* __restrict__ score64, unsigned* __restrict__ cnt) {
    int e = blockIdx.x * blockDim.x + threadIdx.x;
    if (e < EE) atomicAdd(&cnt[bucket_of(score64[e])], 1u);
}

__global__ __launch_bounds__(1024) void k_scan_offs(const unsigned* __restrict__ cnt,
                                                    unsigned* __restrict__ offs) {
    __shared__ unsigned sums[1024];
    const int t = threadIdx.x;
    const int CH = NBUK / 1024;
    const int base = t * CH;
    unsigned s = 0;
    const uint4* c4 = reinterpret_cast<const uint4*>(cnt + base);
    for (int i = 0; i < CH / 4; i++) { uint4 v = c4[i]; s += v.x + v.y + v.z + v.w; }
    sums[t] = s;
    __syncthreads();
    for (int off = 1; off < 1024; off <<= 1) {
        unsigned v = (t >= off) ? sums[t - off] : 0u;
        __syncthreads();
        sums[t] += v;
        __syncthreads();
    }
    unsigned run = (t == 0) ? 0u : sums[t - 1];
    for (int i = 0; i < CH; i++) { unsigned c = cnt[base + i]; offs[base + i] = run; run += c; }
}

__global__ void k_scatter(const double* __restrict__ score64, const unsigned* __restrict__ offs,
                          unsigned* __restrict__ curb, unsigned* __restrict__ slot) {
    int e = blockIdx.x * blockDim.x + threadIdx.x;
    if (e >= EE) return;
    int b = bucket_of(score64[e]);
    unsigned p = offs[b] + atomicAdd(&curb[b], 1u);
    slot[p] = (unsigned)e;
}

__global__ void k_bucket_sort(const unsigned* __restrict__ cnt, const unsigned* __restrict__ offs,
                              unsigned* __restrict__ slot, const double* __restrict__ score64,
                              const int* __restrict__ src, const int* __restrict__ dst,
                              int* __restrict__ spArr, int* __restrict__ tpArr,
                              float* __restrict__ sc32) {
    int b = blockIdx.x * blockDim.x + threadIdx.x;
    if (b >= NBUK) return;
    int n = (int)cnt[b];
    if (n == 0) return;
    unsigned o = offs[b];
    for (int i = 0; i < n; i++) {
        int bi = i;
        unsigned be = slot[o + i];
        double bs = score64[be];
        for (int j = i + 1; j < n; j++) {
            unsigned e2 = slot[o + j];
            double s2 = score64[e2];
            if (s2 > bs || (s2 == bs && e2 < be)) { bi = j; be = e2; bs = s2; }
        }
        if (bi != i) { slot[o + bi] = slot[o + i]; slot[o + i] = be; }
        spArr[o + i] = src[be];
        tpArr[o + i] = dst[be];
        sc32[o + i] = (float)bs;
    }
}

__global__ void k_init_list(unsigned* __restrict__ list0, int* __restrict__ counts) {
    int r = blockIdx.x * blockDim.x + threadIdx.x;
    if (r < ACTE) list0[r] = (unsigned)r;
    if (r == 0) { counts[0] = ACTE; counts[1] = 0; }
}

// ---------------- handshake matching ----------------
__global__ void k_mp1(const int* __restrict__ sp, const int* __restrict__ tp,
                      const unsigned* __restrict__ Lc, int* __restrict__ counts, int cur,
                      unsigned* __restrict__ bc, unsigned* __restrict__ bo,
                      const unsigned* __restrict__ dead) {
    const unsigned gid = blockIdx.x * blockDim.x + threadIdx.x;
    const unsigned gsz = gridDim.x * blockDim.x;
    const int n = counts[cur];
    if (gid == 0) counts[1 - cur] = 0;
    for (unsigned i = gid; i < (unsigned)n; i += gsz) {
        unsigned r = Lc[i];
        int s = sp[r], t = tp[r];
        if (!dead[s] && !dead[t]) { atomicMin(&bc[s], r); atomicMin(&bc[t], r); }
    }
    for (unsigned u = gid; u < NN; u += gsz) bo[u] = 0xFFFFFFFFu;
}

__global__ void k_mp2(const int* __restrict__ sp, const int* __restrict__ tp,
                      const unsigned* __restrict__ Lc, unsigned* __restrict__ Ln,
                      int* __restrict__ counts, int cur,
                      const unsigned* __restrict__ bc,
                      unsigned* __restrict__ dead, unsigned* __restrict__ sel) {
    const unsigned gid = blockIdx.x * blockDim.x + threadIdx.x;
    const unsigned gsz = gridDim.x * blockDim.x;
    const int n = counts[cur];
    for (unsigned i = gid; i < (unsigned)n; i += gsz) {
        unsigned r = Lc[i];
        int s = sp[r], t = tp[r];
        if (ALOADI(&dead[s]) || ALOADI(&dead[t])) continue;
        if (bc[s] == r && bc[t] == r) {
            sel[r] = 1u;
            ASTOREI(&dead[s], 1u);
            ASTOREI(&dead[t], 1u);
        } else {
            int p = atomicAdd(&counts[1 - cur], 1);
            Ln[p] = r;
        }
    }
}

__global__ __launch_bounds__(1024) void k_mtail(const int* __restrict__ sp,
                                                const int* __restrict__ tp,
                                                unsigned* __restrict__ listA,
                                                unsigned* __restrict__ listB,
                                                int* __restrict__ counts, int cur0,
                                                unsigned* __restrict__ best0,
                                                unsigned* __restrict__ best1,
                                                unsigned* __restrict__ dead,
                                                unsigned* __restrict__ sel) {
    const int tid = threadIdx.x, tsz = blockDim.x;
    int cur = cur0;
    while (true) {
        int n = ALOADI(&counts[cur]);
        if (tid == 0) ASTOREI(&counts[1 - cur], 0);
        __syncthreads();
        if (n == 0) break;
        unsigned* Lc = cur ? listB : listA;
        unsigned* Ln = cur ? listA : listB;
        unsigned* bc = cur ? best1 : best0;
        unsigned* bo = cur ? best0 : best1;
        for (int i = tid; i < n; i += tsz) {
            unsigned r = Lc[i];
            int s = sp[r], t = tp[r];
            if (!dead[s] && !dead[t]) { atomicMin(&bc[s], r); atomicMin(&bc[t], r); }
        }
        for (int u = tid; u < NN; u += tsz) bo[u] = 0xFFFFFFFFu;
        __syncthreads();
        for (int i = tid; i < n; i += tsz) {
            unsigned r = Lc[i];
            int s = sp[r], t = tp[r];
            if (dead[s] || dead[t]) continue;
            unsigned bs_ = ALOADI(&bc[s]);
            unsigned bt_ = ALOADI(&bc[t]);
            if (bs_ == r && bt_ == r) {
                sel[r] = 1u;
                dead[s] = 1u;
                dead[t] = 1u;
            } else {
                int p = atomicAdd(&counts[1 - cur], 1);
                Ln[p] = r;
            }
        }
        __syncthreads();
        cur ^= 1;
    }
}

// ---------------- epilogue ----------------
__global__ void k_init_out(float* __restrict__ cscore, float* __restrict__ nbatch) {
    int i = blockIdx.x * blockDim.x + threadIdx.x;
    if (i < NN) { cscore[i] = 100.0f; nbatch[i] = 0.0f; }
}

// ----- parallel scan of sel: phase A (per-block sums, 1024 blocks x 256 thr, 1 elem/thr) -----
__global__ __launch_bounds__(256) void k_sel_part(const unsigned* __restrict__ sel,
                                                  unsigned* __restrict__ bsum) {
    int r = blockIdx.x * 256 + threadIdx.x;
    unsigned f = (r < ACTE) ? sel[r] : 0u;
    unsigned long long m = __ballot(f != 0u);
    __shared__ unsigned ws[4];
    int lane = threadIdx.x & 63, wave = threadIdx.x >> 6;
    if (lane == 0) ws[wave] = (unsigned)__popcll(m);
    __syncthreads();
    if (threadIdx.x == 0) bsum[blockIdx.x] = ws[0] + ws[1] + ws[2] + ws[3];
}

// ----- phase B: one-block exclusive scan of n<=1024 block sums -----
// which==0: sel scan, writes scalars[0]=M.  which==1: survivor scan, writes scalars[1]=numc + numcOut.
__global__ __launch_bounds__(1024) void k_scan_blocks(const unsigned* __restrict__ bsum,
                                                      unsigned* __restrict__ boffs, int n,
                                                      int* __restrict__ scalars, int which,
                                                      float* __restrict__ numcOut) {
    __shared__ unsigned s[1024];
    int t = threadIdx.x;
    unsigned v = (t < n) ? bsum[t] : 0u;
    s[t] = v;
    __syncthreads();
    for (int off = 1; off < 1024; off <<= 1) {
        unsigned u = (t >= off) ? s[t - off] : 0u;
        __syncthreads();
        s[t] += u;
        __syncthreads();
    }
    if (t < n) boffs[t] = s[t] - v;
    if (t == n - 1) {
        if (which == 0) {
            scalars[0] = (int)s[t];
        } else {
            int numc = scalars[0] + (int)s[t];
            scalars[1] = numc;
            numcOut[0] = (float)numc;
        }
    }
}

// ----- phase C: ordered scatter of selected edges -----
__global__ __launch_bounds__(256) void k_sel_write(const unsigned* __restrict__ sel,
                                                   const unsigned* __restrict__ boffs,
                                                   const int* __restrict__ sp,
                                                   const int* __restrict__ tp,
                                                   const float* __restrict__ sc32,
                                                   int* __restrict__ cluster,
                                                   int* __restrict__ mergeS,
                                                   int* __restrict__ mergeT,
                                                   float* __restrict__ cscoreOut) {
    int r = blockIdx.x * 256 + threadIdx.x;
    unsigned f = (r < ACTE) ? sel[r] : 0u;
    unsigned long long m = __ballot(f != 0u);
    int lane = threadIdx.x & 63, wave = threadIdx.x >> 6;
    __shared__ unsigned ws[4];
    if (lane == 0) ws[wave] = (unsigned)__popcll(m);
    __syncthreads();
    if (f) {
        unsigned woff = 0;
        for (int i = 0; i < wave; i++) woff += ws[i];
        unsigned prefix = (unsigned)__popcll(m & ((1ull << lane) - 1ull));
        int i0 = (int)(boffs[blockIdx.x] + woff + prefix);
        int s_ = sp[r], t_ = tp[r];
        cluster[s_] = i0;
        cluster[t_] = i0;
        mergeS[i0] = s_;
        mergeT[i0] = t_;
        cscoreOut[i0] = sc32[r];
    }
}

// ----- survivors: same 3-phase (128 blocks x 256 thr) -----
__global__ __launch_bounds__(256) void k_surv_part(const unsigned* __restrict__ dead,
                                                   unsigned* __restrict__ bsum) {
    int u = blockIdx.x * 256 + threadIdx.x;
    unsigned f = (dead[u] == 0u) ? 1u : 0u;
    unsigned long long m = __ballot(f != 0u);
    __shared__ unsigned ws[4];
    int lane = threadIdx.x & 63, wave = threadIdx.x >> 6;
    if (lane == 0) ws[wave] = (unsigned)__popcll(m);
    __syncthreads();
    if (threadIdx.x == 0) bsum[blockIdx.x] = ws[0] + ws[1] + ws[2] + ws[3];
}

__global__ __launch_bounds__(256) void k_surv_write(const unsigned* __restrict__ dead,
                                                    const unsigned* __restrict__ boffs,
                                                    int* __restrict__ cluster,
                                                    int* __restrict__ survN,
                                                    const int* __restrict__ scalars) {
    int u = blockIdx.x * 256 + threadIdx.x;
    unsigned f = (dead[u] == 0u) ? 1u : 0u;
    unsigned long long m = __ballot(f != 0u);
    int lane = threadIdx.x & 63, wave = threadIdx.x >> 6;
    __shared__ unsigned ws[4];
    if (lane == 0) ws[wave] = (unsigned)__popcll(m);
    __syncthreads();
    if (f) {
        unsigned woff = 0;
        for (int i = 0; i < wave; i++) woff += ws[i];
        unsigned prefix = (unsigned)__popcll(m & ((1ull << lane) - 1ull));
        int idx = (int)(boffs[blockIdx.x] + woff + prefix);
        const int M = scalars[0];
        cluster[u] = M + idx;
        survN[idx] = u;
    }
}

__global__ void k_newx(const float* __restrict__ x, const int* __restrict__ mergeS,
                       const int* __restrict__ mergeT, const int* __restrict__ survN,
                       const int* __restrict__ scalars, float* __restrict__ outx) {
    int gidx = blockIdx.x * blockDim.x + threadIdx.x;
    int c = gidx >> 7;
    int j = gidx & 127;
    const int M = scalars[0], numc = scalars[1];
    float v = 0.0f;
    if (c < M) {
        int s = mergeS[c], t = mergeT[c];
        v = x[s * CC + j] + (s != t ? x[t * CC + j] : 0.0f);
    } else if (c < numc) {
        int u = survN[c - M];
        v = x[u * CC + j];
    }
    outx[gidx] = v;
}

__global__ void k_final(const int* __restrict__ ei, const int* __restrict__ batch,
                        const int* __restrict__ cluster, float* __restrict__ neiOut,
                        float* __restrict__ nbatch, float* __restrict__ clusterOut) {
    int i = blockIdx.x * blockDim.x + threadIdx.x;
    if (i < 2 * EE) neiOut[i] = (float)cluster[ei[i]];
    if (i < NN) {
        clusterOut[i] = (float)cluster[i];
        nbatch[cluster[i]] = (float)batch[i];
    }
}

// ---------------- host ----------------
extern "C" void kernel_launch(void* const* d_in, const int* in_sizes, int n_in,
                              void* d_out, int out_size, void* d_ws, size_t ws_size,
                              hipStream_t stream) {
    const float* x  = (const float*)d_in[0];
    const float* W2 = (const float*)d_in[2];
    const float* b2 = (const float*)d_in[3];
    const float* W1 = (const float*)d_in[4];
    const float* b1 = (const float*)d_in[5];
    const int* ei   = (const int*)d_in[6];
    const int* bat  = (const int*)d_in[7];
    const int* src = ei;
    const int* dst = ei + EE;
    float* out = (float*)d_out;

    char* p = (char*)d_ws;
    auto take = [&](size_t bytes) -> char* {
        char* r = p;
        p += (bytes + 255) & ~(size_t)255;
        return r;
    };
    double*   Abuf    = (double*)take((size_t)NN * CTWO * 8);
    double*   Bbuf    = (double*)take((size_t)NN * CTWO * 8);
    double*   score64 = (double*)take((size_t)EE * 8);
    unsigned* cnt     = (unsigned*)take((size_t)NBUK * 4);
    unsigned* offs    = (unsigned*)take((size_t)NBUK * 4);
    unsigned* curb    = (unsigned*)take((size_t)NBUK * 4);
    unsigned* slot    = (unsigned*)take((size_t)EE * 4);
    int*      spArr   = (int*)take((size_t)EE * 4);
    int*      tpArr   = (int*)take((size_t)EE * 4);
    float*    sc32    = (float*)take((size_t)EE * 4);
    unsigned* list0   = (unsigned*)take((size_t)NBUK * 4);
    unsigned* list1   = (unsigned*)take((size_t)NBUK * 4);
    unsigned* best0   = (unsigned*)take((size_t)NN * 4);
    unsigned* best1   = (unsigned*)take((size_t)NN * 4);
    unsigned* dead    = (unsigned*)take((size_t)NN * 4);
    unsigned* sel     = (unsigned*)take((size_t)NBUK * 4);
    int*      cluster = (int*)take((size_t)NN * 4);
    int*      mergeS  = (int*)take((size_t)NN * 4);
    int*      mergeT  = (int*)take((size_t)NN * 4);
    int*      survN   = (int*)take((size_t)NN * 4);
    unsigned* selBsum = (unsigned*)take(1024 * 4);
    unsigned* selBoff = (unsigned*)take(1024 * 4);
    unsigned* survBsum= (unsigned*)take(128 * 4);
    unsigned* survBoff= (unsigned*)take(128 * 4);
    int*      counts  = (int*)take(256);
    int*      scalars = (int*)take(256);

    hipMemsetAsync(cnt, 0, (size_t)NBUK * 4, stream);
    hipMemsetAsync(curb, 0, (size_t)NBUK * 4, stream);
    hipMemsetAsync(sel, 0, (size_t)NBUK * 4, stream);
    hipMemsetAsync(dead, 0, (size_t)NN * 4, stream);
    hipMemsetAsync(best0, 0xFF, (size_t)NN * 4, stream);
    hipMemsetAsync(best1, 0xFF, (size_t)NN * 4, stream);

    k_gemm1<<<dim3(NN / 32, 2), 256, 0, stream>>>(x, W2, Abuf, Bbuf);
    k_edge_score<<<EE / 4, 256, 0, stream>>>(Abuf, Bbuf, src, dst, b2, W1, b1, score64,
                                             out + OFF_SCORE);
    k_bucket_count<<<EE / 256, 256, 0, stream>>>(score64, cnt);
    k_scan_offs<<<1, 1024, 0, stream>>>(cnt, offs);
    k_scatter<<<EE / 256, 256, 0, stream>>>(score64, offs, curb, slot);
    k_bucket_sort<<<NBUK / 256, 256, 0, stream>>>(cnt, offs, slot, score64, src, dst, spArr,
                                                  tpArr, sc32);
    k_init_list<<<NBUK / 256, 256, 0, stream>>>(list0, counts);

    const int NBIG = 10;
    for (int r = 0; r < NBIG; ++r) {
        int cur = r & 1;
        unsigned* Lc = cur ? list1 : list0;
        unsigned* Ln = cur ? list0 : list1;
        unsigned* bc = cur ? best1 : best0;
        unsigned* bo = cur ? best0 : best1;
        k_mp1<<<1024, 256, 0, stream>>>(spArr, tpArr, Lc, counts, cur, bc, bo, dead);
        k_mp2<<<1024, 256, 0, stream>>>(spArr, tpArr, Lc, Ln, counts, cur, bc, dead, sel);
    }
    k_mtail<<<1, 1024, 0, stream>>>(spArr, tpArr, list0, list1, counts, NBIG & 1, best0, best1,
                                    dead, sel);

    k_init_out<<<NN / 256, 256, 0, stream>>>(out + OFF_CSCORE, out + OFF_NBATCH);

    // parallel sel-scan + scatter (replaces the 411 us single-block k_sel_fill)
    k_sel_part<<<1024, 256, 0, stream>>>(sel, selBsum);
    k_scan_blocks<<<1, 1024, 0, stream>>>(selBsum, selBoff, 1024, scalars, 0, out + OFF_NUMC);
    k_sel_write<<<1024, 256, 0, stream>>>(sel, selBoff, spArr, tpArr, sc32, cluster, mergeS,
                                          mergeT, out + OFF_CSCORE);
    // parallel survivor-scan
    k_surv_part<<<NN / 256, 256, 0, stream>>>(dead, survBsum);
    k_scan_blocks<<<1, 1024, 0, stream>>>(survBsum, survBoff, NN / 256, scalars, 1,
                                          out + OFF_NUMC);
    k_surv_write<<<NN / 256, 256, 0, stream>>>(dead, survBoff, cluster, survN, scalars);

    k_newx<<<(NN * CC) / 256, 256, 0, stream>>>(x, mergeS, mergeT, survN, scalars, out + OFF_NEWX);
    k_final<<<(2 * EE) / 256, 256, 0, stream>>>(ei, bat, cluster, out + OFF_NEI, out + OFF_NBATCH,
                                                out + OFF_CLUST);
}